// Round 14
// baseline (271.715 us; speedup 1.0000x reference)
//
#include <hip/hip_runtime.h>
#include <stdint.h>

#define DIN   4096
#define DOUT  4096
#define MTOT  8192
#define NT    64                      /* K-tiles of BK=64 */

#define BM    256
#define BN    256
#define GRID_M (MTOT / BM)            /* 32 */
#define GRID_N (DOUT / BN)            /* 16 */
#define NWG   (GRID_M * GRID_N)       /* 512 */

typedef __attribute__((ext_vector_type(4))) float        f32x4;
typedef __attribute__((ext_vector_type(4))) int          i32x4;
typedef __attribute__((ext_vector_type(4))) unsigned int u32x4;
typedef __attribute__((ext_vector_type(2))) unsigned int u32x2;
typedef __attribute__((ext_vector_type(8))) short        bf16x8;

__device__ __forceinline__ unsigned int pack_bf2_rne(float a, float b) {
  unsigned int ua = __builtin_bit_cast(unsigned int, a);
  unsigned int ub = __builtin_bit_cast(unsigned int, b);
  ua += 0x7fffu + ((ua >> 16) & 1u);
  ub += 0x7fffu + ((ub >> 16) & 1u);
  return (ua >> 16) | (ub & 0xffff0000u);
}

// (w - off) integer, |v| <= 135 < 256 -> exact in bf16.
__device__ __forceinline__ unsigned int pack_bf2_exact(int a, int b) {
  unsigned int ua = __builtin_bit_cast(unsigned int, (float)a);
  unsigned int ub = __builtin_bit_cast(unsigned int, (float)b);
  return (ua >> 16) | (ub & 0xffff0000u);
}

// ---- merged pre-pass (r8, proven): x->bf16 and (w-off)->bf16, 16KiB units of
// [128 rows][64 k], pre-swizzled: byte layout row*128 + ((chunk*16)^((row&7)<<4))
#define TOTA (MTOT * (DIN / 8))
#define TOTB (DOUT * (DIN / 8))
__global__ __launch_bounds__(256) void conv_kernel(const float* __restrict__ X,
                                                   u32x4* __restrict__ wsA,
                                                   const int* __restrict__ W,
                                                   const int* __restrict__ Off,
                                                   u32x4* __restrict__ wsB) {
  for (int idx = blockIdx.x * 256 + threadIdx.x; idx < TOTA + TOTB;
       idx += gridDim.x * 256) {
    if (idx < TOTA) {
      const int m  = idx >> 9;
      const int c  = idx & 511;
      const int kt = c >> 3, ch = c & 7;
      const int rb = m >> 7, row = m & 127;
      const f32x4* src = (const f32x4*)(X + ((long)m << 12) + kt * 64 + ch * 8);
      f32x4 f0 = src[0], f1 = src[1];
      u32x4 d;
      d[0] = pack_bf2_rne(f0[0], f0[1]);
      d[1] = pack_bf2_rne(f0[2], f0[3]);
      d[2] = pack_bf2_rne(f1[0], f1[1]);
      d[3] = pack_bf2_rne(f1[2], f1[3]);
      wsA[(long)(rb * NT + kt) * 1024 + row * 8 + (ch ^ (row & 7))] = d;
    } else {
      const int j  = idx - TOTA;
      const int n  = j >> 9;
      const int c  = j & 511;
      const int kt = c >> 3, ch = c & 7;
      const int nb = n >> 7, row = n & 127;
      const i32x4* src = (const i32x4*)(W + ((long)n << 12) + kt * 64 + ch * 8);
      const int off = Off[n];
      i32x4 w0 = src[0], w1 = src[1];
      u32x4 d;
      d[0] = pack_bf2_exact(w0[0] - off, w0[1] - off);
      d[1] = pack_bf2_exact(w0[2] - off, w0[3] - off);
      d[2] = pack_bf2_exact(w1[0] - off, w1[1] - off);
      d[3] = pack_bf2_exact(w1[2] - off, w1[3] - off);
      wsB[(long)(nb * NT + kt) * 1024 + row * 8 + (ch ^ (row & 7))] = d;
    }
  }
}

// ====== r13 GEMM (quadrant phases) with issue-rebalanced staging ======
// Phase = C-quadrant (64 rows x 32 cols) x full K=64:
//  ph1: rd B-lo(4)+A-lo(8) ; (no stage)            ; LGKM0 ; 16 MFMA aPxbP ; BAR
//  ph2: rd B-hi(4) ; stage A0(t+1)+A1(t+1)->ABUF   ; LGKM0 ; 16 MFMA aPxbQ ; BAR
//  ph3: rd A-hi(8) ; stage B0(t+2)->BBUF           ; LGKM0 ; 16 MFMA aQxbP ; BAR
//  ph4: (no reads) ; stage B1(t+2)->BBUF ; WAITV(4); 16 MFMA aQxbQ ; BAR
// The 12-read ph1 no longer contends with staging issue; ph4 absorbs it.
// Ledger (2 loads/stage, per-tile issue order A0,A1@ph2 B0@ph3 B1@ph4):
//  entering ph4 gate: B0,B1(t+1)[t-1 ph3/4] + A0,A1(t+1)[t ph2] + B0(t+2)[t ph3]
//  + B1(t+2)[t ph4] = 12 loads; WAITV(4) retires 8 = ALL of tile t+1 BEFORE the
//  end-BAR -> retire->BAR->read holds. WAR: B of current buf fully read by ph2's
//  LGKM0+BAR -> ph3/4 B-staging safe; A(t+1) targets the other buffer.
// Tail: WAITV(0) at t=62; t=63 compute-only. Identical invariants to r13.

#define BAR()   __builtin_amdgcn_s_barrier()
#define SB()    __builtin_amdgcn_sched_barrier(0)
#define LGKM0() asm volatile("s_waitcnt lgkmcnt(0)" ::: "memory")
#define WAITV(N) asm volatile("s_waitcnt vmcnt(" #N ")" ::: "memory")

typedef __attribute__((address_space(3))) const char* ldsp;

#define DSR(dst, p, IMM) \
  asm volatile("ds_read_b128 %0, %1 offset:" #IMM : "=v"(dst) : "v"(p))

#define STAGE(ldsArr, bufc, h, basePtr, t)                                      \
  { const u32x4* s_ = (basePtr) + (long)(t) * 1024;                             \
    _Pragma("unroll")                                                           \
    for (int i_ = 0; i_ < 2; ++i_) {                                            \
      const int o_ = tid + i_ * 512;                                            \
      __builtin_amdgcn_global_load_lds(                                         \
          (const __attribute__((address_space(1))) void*)(s_ + o_),             \
          (__attribute__((address_space(3))) void*)(&ldsArr[bufc][h][0][0] + o_),\
          16, 0, 0);                                                            \
    } }

// A rows 0..63 (4 m-frags) x both k-halves
#define RD_A_LO(pAc0, pAc1)                                                     \
  DSR(aP[0][0], pAc0, 0);    DSR(aP[1][0], pAc0, 2048);                         \
  DSR(aP[2][0], pAc0, 4096); DSR(aP[3][0], pAc0, 6144);                         \
  DSR(aP[0][1], pAc1, 0);    DSR(aP[1][1], pAc1, 2048);                         \
  DSR(aP[2][1], pAc1, 4096); DSR(aP[3][1], pAc1, 6144);
// A rows 64..127
#define RD_A_HI(pAc0, pAc1)                                                     \
  DSR(aQ[0][0], pAc0, 8192);  DSR(aQ[1][0], pAc0, 10240);                       \
  DSR(aQ[2][0], pAc0, 12288); DSR(aQ[3][0], pAc0, 14336);                       \
  DSR(aQ[0][1], pAc1, 8192);  DSR(aQ[1][1], pAc1, 10240);                       \
  DSR(aQ[2][1], pAc1, 12288); DSR(aQ[3][1], pAc1, 14336);
// B cols 0..31 (2 n-frags) x both k-halves
#define RD_B_LO(pBc0, pBc1)                                                     \
  DSR(bP[0][0], pBc0, 0); DSR(bP[1][0], pBc0, 2048);                            \
  DSR(bP[0][1], pBc1, 0); DSR(bP[1][1], pBc1, 2048);
// B cols 32..63
#define RD_B_HI(pBc0, pBc1)                                                     \
  DSR(bQ[0][0], pBc0, 4096); DSR(bQ[1][0], pBc0, 6144);                         \
  DSR(bQ[0][1], pBc1, 4096); DSR(bQ[1][1], pBc1, 6144);

#define MMA16Q(aS_, bS_, mb, nb)                                                \
  __builtin_amdgcn_s_setprio(1);                                                \
  { _Pragma("unroll") for (int k_ = 0; k_ < 2; ++k_)                            \
    { _Pragma("unroll") for (int m_ = 0; m_ < 4; ++m_)                          \
      { _Pragma("unroll") for (int n_ = 0; n_ < 2; ++n_)                        \
          acc[(mb) + m_][(nb) + n_] = __builtin_amdgcn_mfma_f32_16x16x32_bf16(  \
              aS_[m_][k_], bS_[n_][k_], acc[(mb) + m_][(nb) + n_], 0, 0, 0);    \
  } } }                                                                         \
  __builtin_amdgcn_s_setprio(0);

#define TILE(pAc0, pAc1, pBc0, pBc1, ABUF, BBUF, t, SA, SBf, WV)                \
  RD_B_LO(pBc0, pBc1) RD_A_LO(pAc0, pAc1)                                       \
  LGKM0(); SB(); MMA16Q(aP, bP, 0, 0) BAR();                                    \
  RD_B_HI(pBc0, pBc1)                                                           \
  if (SA) { STAGE(ldsA, ABUF, 0, bA0, (t) + 1)                                  \
            STAGE(ldsA, ABUF, 1, bA1, (t) + 1) }                                \
  LGKM0(); SB(); MMA16Q(aP, bQ, 0, 2) BAR();                                    \
  RD_A_HI(pAc0, pAc1)                                                           \
  if (SBf) { STAGE(ldsB, BBUF, 0, bB0, (t) + 2) }                               \
  LGKM0(); SB(); MMA16Q(aQ, bP, 4, 0) BAR();                                    \
  if (SBf) { STAGE(ldsB, BBUF, 1, bB1, (t) + 2) }                               \
  WV; SB(); MMA16Q(aQ, bQ, 4, 2) BAR();

__global__ __launch_bounds__(512, 2) void gemm8_kernel(
    const u32x4* __restrict__ wsA, const u32x4* __restrict__ wsB,
    const float* __restrict__ Scale, float* __restrict__ Out) {
  __shared__ u32x4 ldsA[2][2][128][8];   // [buf][half][row][chunk16] = 64 KiB
  __shared__ u32x4 ldsB[2][2][128][8];

  const int tid  = threadIdx.x;
  const int lane = tid & 63;
  const int wid  = tid >> 6;
  const int wr   = wid >> 2;     // A half
  const int wc   = wid & 3;      // 64-col N slice
  const int wch  = wc >> 1;      // B half
  const int wcl  = wc & 1;

  int gid = (int)blockIdx.x;
  gid = (gid & 7) * (NWG >> 3) + (gid >> 3);   // bijective XCD swizzle (512%8==0)
  const int wg_m = gid / GRID_N;
  const int wg_n = gid % GRID_N;

  const int riA = lane & 15;
  const int c0  = lane >> 4;
  const int cs0 = c0 ^ (riA & 7);              // logical chunk c0   ^ row-swz
  const int cs1 = (4 + c0) ^ (riA & 7);        // logical chunk 4+c0 ^ row-swz

  // per-wave LDS read base pointers (AS3, 32-bit); m strides are literal offsets
  ldsp pA0c0 = (ldsp)&ldsA[0][wr][riA][cs0];
  ldsp pA0c1 = (ldsp)&ldsA[0][wr][riA][cs1];
  ldsp pA1c0 = (ldsp)&ldsA[1][wr][riA][cs0];
  ldsp pA1c1 = (ldsp)&ldsA[1][wr][riA][cs1];
  ldsp pB0c0 = (ldsp)&ldsB[0][wch][wcl * 64 + riA][cs0];
  ldsp pB0c1 = (ldsp)&ldsB[0][wch][wcl * 64 + riA][cs1];
  ldsp pB1c0 = (ldsp)&ldsB[1][wch][wcl * 64 + riA][cs0];
  ldsp pB1c1 = (ldsp)&ldsB[1][wch][wcl * 64 + riA][cs1];

  const u32x4* bA0 = wsA + (long)(wg_m * 2 + 0) * NT * 1024;
  const u32x4* bA1 = wsA + (long)(wg_m * 2 + 1) * NT * 1024;
  const u32x4* bB0 = wsB + (long)(wg_n * 2 + 0) * NT * 1024;
  const u32x4* bB1 = wsB + (long)(wg_n * 2 + 1) * NT * 1024;

  f32x4 acc[8][4];
#pragma unroll
  for (int m = 0; m < 8; ++m)
#pragma unroll
    for (int n = 0; n < 4; ++n) acc[m][n] = (f32x4){0.f, 0.f, 0.f, 0.f};

  bf16x8 aP[4][2], aQ[4][2], bP[2][2], bQ[2][2];

  // prologue: tile0 all 4 half-tiles + tile1 B halves; retire tile0 (vmcnt(4))
  STAGE(ldsB, 0, 0, bB0, 0) STAGE(ldsA, 0, 0, bA0, 0)
  STAGE(ldsB, 0, 1, bB1, 0) STAGE(ldsA, 0, 1, bA1, 0)
  STAGE(ldsB, 1, 0, bB0, 1) STAGE(ldsB, 1, 1, bB1, 1)
  WAITV(4); BAR();

#pragma unroll 1
  for (int it = 0; it < 31; ++it) {            // tiles 0..61
    const int t = 2 * it;
    TILE(pA0c0, pA0c1, pB0c0, pB0c1, 1, 0, t,     1, 1, WAITV(4))
    TILE(pA1c0, pA1c1, pB1c0, pB1c1, 0, 1, t + 1, 1, 1, WAITV(4))
  }
  TILE(pA0c0, pA0c1, pB0c0, pB0c1, 1, 0, 62, 1, 0, WAITV(0))  // stage A(63), drain
  TILE(pA1c0, pA1c1, pB1c0, pB1c1, 0, 1, 63, 0, 0, )          // compute only

  // epilogue: out = acc * scale[col]; C/D map: col=lane&15, row=(lane>>4)*4+j
  const int col0 = wg_n * BN + wc * 64 + (lane & 15);
  const int row0 = wg_m * BM + wr * 128 + ((lane >> 4) << 2);
#pragma unroll
  for (int n = 0; n < 4; ++n) {
    const int col = col0 + n * 16;
    const float s = Scale[col];
#pragma unroll
    for (int m = 0; m < 8; ++m) {
      const int r = row0 + m * 16;
#pragma unroll
      for (int j = 0; j < 4; ++j)
        Out[(long)(r + j) * DOUT + col] = acc[m][n][j] * s;
    }
  }
}

// ================= fallback: fused 128x128 (round-1, proven) =================
__global__ __launch_bounds__(256, 2) void gemm_fused_kernel(
    const float* __restrict__ X, const int* __restrict__ W,
    const int* __restrict__ Off, const float* __restrict__ Scale,
    float* __restrict__ Out) {
  __shared__ char ldsA[2][128 * 64 * 2];
  __shared__ char ldsB[2][128 * 64 * 2];

  const int tid  = threadIdx.x;
  const int lane = tid & 63;
  const int wid  = tid >> 6;
  const int fwr  = wid >> 1;
  const int fwc  = wid & 1;

  int gid = (int)blockIdx.x;
  gid = (gid & 7) * (2048 >> 3) + (gid >> 3);
  const int wg_m = gid / 32;
  const int wg_n = gid % 32;
  const int brow = wg_m * 128;
  const int bcol = wg_n * 128;

  f32x4 acc[4][4];
#pragma unroll
  for (int m = 0; m < 4; ++m)
#pragma unroll
    for (int n = 0; n < 4; ++n) acc[m][n] = (f32x4){0.f, 0.f, 0.f, 0.f};

  int aoff[2][4], boff[2][4];
#pragma unroll
  for (int kk = 0; kk < 2; ++kk)
#pragma unroll
    for (int m = 0; m < 4; ++m) {
      const int kb = kk * 64 + ((lane >> 4) << 4);
      const int ra = fwr * 64 + m * 16 + (lane & 15);
      const int rb = fwc * 64 + m * 16 + (lane & 15);
      aoff[kk][m] = ra * 128 + (kb ^ ((ra & 7) << 4));
      boff[kk][m] = rb * 128 + (kb ^ ((rb & 7) << 4));
    }

  long xo[8], wo[8];
  int lo[8], ofv[8];
#pragma unroll
  for (int i = 0; i < 8; ++i) {
    const int idx = tid + i * 256;
    const int row = idx >> 4, c4 = idx & 15;
    xo[i] = (long)(brow + row) * DIN + c4 * 4;
    wo[i] = (long)(bcol + row) * DIN + c4 * 4;
    lo[i] = row * 128 + ((c4 * 8) ^ ((row & 7) << 4));
    ofv[i] = Off[bcol + row];
  }
  {
#pragma unroll
    for (int i = 0; i < 8; ++i) {
      f32x4 f = *(const f32x4*)(X + xo[i]);
      u32x2 d;
      d[0] = pack_bf2_rne(f[0], f[1]);
      d[1] = pack_bf2_rne(f[2], f[3]);
      *(u32x2*)(&ldsA[0][lo[i]]) = d;
    }
#pragma unroll
    for (int i = 0; i < 8; ++i) {
      i32x4 w = *(const i32x4*)(W + wo[i]);
      u32x2 d;
      d[0] = pack_bf2_exact(w[0] - ofv[i], w[1] - ofv[i]);
      d[1] = pack_bf2_exact(w[2] - ofv[i], w[3] - ofv[i]);
      *(u32x2*)(&ldsB[0][lo[i]]) = d;
    }
  }
  __syncthreads();
#pragma unroll 1
  for (int kt = 0; kt < NT; ++kt) {
    const int cur = kt & 1;
    const bool pf = (kt + 1 < NT);
    f32x4 fa[8];
    i32x4 fb[8];
    if (pf) {
      const int ko = (kt + 1) * 64;
#pragma unroll
      for (int i = 0; i < 8; ++i) fa[i] = *(const f32x4*)(X + xo[i] + ko);
#pragma unroll
      for (int i = 0; i < 8; ++i) fb[i] = *(const i32x4*)(W + wo[i] + ko);
    }
#pragma unroll
    for (int kk = 0; kk < 2; ++kk) {
      bf16x8 fa2[4], fb2[4];
#pragma unroll
      for (int m = 0; m < 4; ++m)
        fa2[m] = __builtin_bit_cast(bf16x8, *(const u32x4*)(&ldsA[cur][aoff[kk][m]]));
#pragma unroll
      for (int n = 0; n < 4; ++n)
        fb2[n] = __builtin_bit_cast(bf16x8, *(const u32x4*)(&ldsB[cur][boff[kk][n]]));
#pragma unroll
      for (int m = 0; m < 4; ++m)
#pragma unroll
        for (int n = 0; n < 4; ++n)
          acc[m][n] = __builtin_amdgcn_mfma_f32_16x16x32_bf16(fa2[m], fb2[n], acc[m][n], 0, 0, 0);
    }
    if (pf) {
      char* dA = ldsA[cur ^ 1];
      char* dB = ldsB[cur ^ 1];
#pragma unroll
      for (int i = 0; i < 8; ++i) {
        u32x2 d;
        d[0] = pack_bf2_rne(fa[i][0], fa[i][1]);
        d[1] = pack_bf2_rne(fa[i][2], fa[i][3]);
        *(u32x2*)(&dA[lo[i]]) = d;
      }
#pragma unroll
      for (int i = 0; i < 8; ++i) {
        u32x2 d;
        d[0] = pack_bf2_exact(fb[i][0] - ofv[i], fb[i][1] - ofv[i]);
        d[1] = pack_bf2_exact(fb[i][2] - ofv[i], fb[i][3] - ofv[i]);
        *(u32x2*)(&dB[lo[i]]) = d;
      }
    }
    __syncthreads();
  }

  const int col0 = bcol + fwc * 64 + (lane & 15);
  const int row0 = brow + fwr * 64 + ((lane >> 4) << 2);
#pragma unroll
  for (int n = 0; n < 4; ++n) {
    const int col = col0 + n * 16;
    const float s = Scale[col];
#pragma unroll
    for (int m = 0; m < 4; ++m) {
      const int r = row0 + m * 16;
#pragma unroll
      for (int j = 0; j < 4; ++j)
        Out[(long)(r + j) * DOUT + col] = acc[m][n][j] * s;
    }
  }
}

extern "C" void kernel_launch(void* const* d_in, const int* in_sizes, int n_in,
                              void* d_out, int out_size, void* d_ws, size_t ws_size,
                              hipStream_t stream) {
  (void)in_sizes; (void)n_in; (void)out_size;
  const float* X  = (const float*)d_in[0];
  const int*   W  = (const int*)d_in[1];
  const float* Sc = (const float*)d_in[2];
  const int*   Of = (const int*)d_in[3];
  float* Out = (float*)d_out;

  const size_t needA = (size_t)MTOT * DIN * 2;
  const size_t needB = (size_t)DOUT * DIN * 2;
  if (ws_size >= needA + needB) {
    u32x4* wsA = (u32x4*)d_ws;
    u32x4* wsB = (u32x4*)((char*)d_ws + needA);
    conv_kernel<<<3072, 256, 0, stream>>>(X, wsA, W, Of, wsB);
    gemm8_kernel<<<NWG, 512, 0, stream>>>(wsA, wsB, Sc, Out);
  } else {
    gemm_fused_kernel<<<2048, 256, 0, stream>>>(X, W, Of, Sc, Out);
  }
}

// Round 15
// 267.895 us; speedup vs baseline: 1.0143x; 1.0143x over previous
//
#include <hip/hip_runtime.h>
#include <stdint.h>

#define DIN   4096
#define DOUT  4096
#define MTOT  8192
#define NT    64                      /* K-tiles of BK=64 */

#define BM    256
#define BN    256
#define GRID_M (MTOT / BM)            /* 32 */
#define GRID_N (DOUT / BN)            /* 16 */
#define NWG   (GRID_M * GRID_N)       /* 512 */

typedef __attribute__((ext_vector_type(4))) float        f32x4;
typedef __attribute__((ext_vector_type(4))) int          i32x4;
typedef __attribute__((ext_vector_type(4))) unsigned int u32x4;
typedef __attribute__((ext_vector_type(2))) unsigned int u32x2;
typedef __attribute__((ext_vector_type(8))) short        bf16x8;

__device__ __forceinline__ unsigned int pack_bf2_rne(float a, float b) {
  unsigned int ua = __builtin_bit_cast(unsigned int, a);
  unsigned int ub = __builtin_bit_cast(unsigned int, b);
  ua += 0x7fffu + ((ua >> 16) & 1u);
  ub += 0x7fffu + ((ub >> 16) & 1u);
  return (ua >> 16) | (ub & 0xffff0000u);
}

// (w - off) integer, |v| <= 135 < 256 -> exact in bf16.
__device__ __forceinline__ unsigned int pack_bf2_exact(int a, int b) {
  unsigned int ua = __builtin_bit_cast(unsigned int, (float)a);
  unsigned int ub = __builtin_bit_cast(unsigned int, (float)b);
  return (ua >> 16) | (ub & 0xffff0000u);
}

// ---- merged pre-pass (r8, proven): x->bf16 and (w-off)->bf16, 16KiB units of
// [128 rows][64 k], pre-swizzled: byte layout row*128 + ((chunk*16)^((row&7)<<4))
#define TOTA (MTOT * (DIN / 8))
#define TOTB (DOUT * (DIN / 8))
__global__ __launch_bounds__(256) void conv_kernel(const float* __restrict__ X,
                                                   u32x4* __restrict__ wsA,
                                                   const int* __restrict__ W,
                                                   const int* __restrict__ Off,
                                                   u32x4* __restrict__ wsB) {
  for (int idx = blockIdx.x * 256 + threadIdx.x; idx < TOTA + TOTB;
       idx += gridDim.x * 256) {
    if (idx < TOTA) {
      const int m  = idx >> 9;
      const int c  = idx & 511;
      const int kt = c >> 3, ch = c & 7;
      const int rb = m >> 7, row = m & 127;
      const f32x4* src = (const f32x4*)(X + ((long)m << 12) + kt * 64 + ch * 8);
      f32x4 f0 = src[0], f1 = src[1];
      u32x4 d;
      d[0] = pack_bf2_rne(f0[0], f0[1]);
      d[1] = pack_bf2_rne(f0[2], f0[3]);
      d[2] = pack_bf2_rne(f1[0], f1[1]);
      d[3] = pack_bf2_rne(f1[2], f1[3]);
      wsA[(long)(rb * NT + kt) * 1024 + row * 8 + (ch ^ (row & 7))] = d;
    } else {
      const int j  = idx - TOTA;
      const int n  = j >> 9;
      const int c  = j & 511;
      const int kt = c >> 3, ch = c & 7;
      const int nb = n >> 7, row = n & 127;
      const i32x4* src = (const i32x4*)(W + ((long)n << 12) + kt * 64 + ch * 8);
      const int off = Off[n];
      i32x4 w0 = src[0], w1 = src[1];
      u32x4 d;
      d[0] = pack_bf2_exact(w0[0] - off, w0[1] - off);
      d[1] = pack_bf2_exact(w0[2] - off, w0[3] - off);
      d[2] = pack_bf2_exact(w1[0] - off, w1[1] - off);
      d[3] = pack_bf2_exact(w1[2] - off, w1[3] - off);
      wsB[(long)(nb * NT + kt) * 1024 + row * 8 + (ch ^ (row & 7))] = d;
    }
  }
}

// ====== r8 GEMM + m201 C-QUADRANT phase decomposition (12/4/8/0 reads) ======
// Phase = C-quadrant (64 rows x 32 cols) x full K=64:
//  ph1: rd B-lo(4)+A-lo(8) ; stage A0(t+1)->ABUF ; LGKM0 ; 16 MFMA aPxbP ; BAR
//  ph2: rd B-hi(4)         ; stage A1(t+1)->ABUF ; LGKM0 ; 16 MFMA aPxbQ ; BAR
//  ph3: rd A-hi(8)         ; stage B0(t+2)->BBUF ; LGKM0 ; 16 MFMA aQxbP ; BAR
//  ph4: (no reads)         ; stage B1(t+2)->BBUF ; WAITV(4) ; 16 MFMA aQxbQ ; BAR
// A-frags persist 2 phases, B-frags 2; ph4 is read-free (pure MFMA under the
// vmcnt gate). Ledgers identical to r8 (proven): B of current buf fully read by
// ph2's LGKM0 + BAR -> ph3/4 staging into it WAR-safe; A(t+1) -> other buffer;
// WAITV(4) at ph4 (12 outstanding, retires 8 = all of t+1) precedes the end-BAR
// -> retire->BAR->read holds. Tail: WAITV(0) at t=62, t=63 compute-only.

#define BAR()   __builtin_amdgcn_s_barrier()
#define SB()    __builtin_amdgcn_sched_barrier(0)
#define LGKM0() asm volatile("s_waitcnt lgkmcnt(0)" ::: "memory")
#define WAITV(N) asm volatile("s_waitcnt vmcnt(" #N ")" ::: "memory")

typedef __attribute__((address_space(3))) const char* ldsp;

#define DSR(dst, p, IMM) \
  asm volatile("ds_read_b128 %0, %1 offset:" #IMM : "=v"(dst) : "v"(p))

#define STAGE(ldsArr, bufc, h, basePtr, t)                                      \
  { const u32x4* s_ = (basePtr) + (long)(t) * 1024;                             \
    _Pragma("unroll")                                                           \
    for (int i_ = 0; i_ < 2; ++i_) {                                            \
      const int o_ = tid + i_ * 512;                                            \
      __builtin_amdgcn_global_load_lds(                                         \
          (const __attribute__((address_space(1))) void*)(s_ + o_),             \
          (__attribute__((address_space(3))) void*)(&ldsArr[bufc][h][0][0] + o_),\
          16, 0, 0);                                                            \
    } }

// A rows 0..63 (4 m-frags) x both k-halves
#define RD_A_LO(pAc0, pAc1)                                                     \
  DSR(aP[0][0], pAc0, 0);    DSR(aP[1][0], pAc0, 2048);                         \
  DSR(aP[2][0], pAc0, 4096); DSR(aP[3][0], pAc0, 6144);                         \
  DSR(aP[0][1], pAc1, 0);    DSR(aP[1][1], pAc1, 2048);                         \
  DSR(aP[2][1], pAc1, 4096); DSR(aP[3][1], pAc1, 6144);
// A rows 64..127
#define RD_A_HI(pAc0, pAc1)                                                     \
  DSR(aQ[0][0], pAc0, 8192);  DSR(aQ[1][0], pAc0, 10240);                       \
  DSR(aQ[2][0], pAc0, 12288); DSR(aQ[3][0], pAc0, 14336);                       \
  DSR(aQ[0][1], pAc1, 8192);  DSR(aQ[1][1], pAc1, 10240);                       \
  DSR(aQ[2][1], pAc1, 12288); DSR(aQ[3][1], pAc1, 14336);
// B cols 0..31 (2 n-frags) x both k-halves
#define RD_B_LO(pBc0, pBc1)                                                     \
  DSR(bP[0][0], pBc0, 0); DSR(bP[1][0], pBc0, 2048);                            \
  DSR(bP[0][1], pBc1, 0); DSR(bP[1][1], pBc1, 2048);
// B cols 32..63
#define RD_B_HI(pBc0, pBc1)                                                     \
  DSR(bQ[0][0], pBc0, 4096); DSR(bQ[1][0], pBc0, 6144);                         \
  DSR(bQ[0][1], pBc1, 4096); DSR(bQ[1][1], pBc1, 6144);

#define MMA16Q(aS_, bS_, mb, nb)                                                \
  __builtin_amdgcn_s_setprio(1);                                                \
  { _Pragma("unroll") for (int k_ = 0; k_ < 2; ++k_)                            \
    { _Pragma("unroll") for (int m_ = 0; m_ < 4; ++m_)                          \
      { _Pragma("unroll") for (int n_ = 0; n_ < 2; ++n_)                        \
          acc[(mb) + m_][(nb) + n_] = __builtin_amdgcn_mfma_f32_16x16x32_bf16(  \
              aS_[m_][k_], bS_[n_][k_], acc[(mb) + m_][(nb) + n_], 0, 0, 0);    \
  } } }                                                                         \
  __builtin_amdgcn_s_setprio(0);

#define TILE(pAc0, pAc1, pBc0, pBc1, ABUF, BBUF, t, SA, SBf, WV)                \
  RD_B_LO(pBc0, pBc1) RD_A_LO(pAc0, pAc1)                                       \
  if (SA) { STAGE(ldsA, ABUF, 0, bA0, (t) + 1) }                                \
  LGKM0(); SB(); MMA16Q(aP, bP, 0, 0) BAR();                                    \
  RD_B_HI(pBc0, pBc1)                                                           \
  if (SA) { STAGE(ldsA, ABUF, 1, bA1, (t) + 1) }                                \
  LGKM0(); SB(); MMA16Q(aP, bQ, 0, 2) BAR();                                    \
  RD_A_HI(pAc0, pAc1)                                                           \
  if (SBf) { STAGE(ldsB, BBUF, 0, bB0, (t) + 2) }                               \
  LGKM0(); SB(); MMA16Q(aQ, bP, 4, 0) BAR();                                    \
  if (SBf) { STAGE(ldsB, BBUF, 1, bB1, (t) + 2) }                               \
  WV; SB(); MMA16Q(aQ, bQ, 4, 2) BAR();

__global__ __launch_bounds__(512, 2) void gemm8_kernel(
    const u32x4* __restrict__ wsA, const u32x4* __restrict__ wsB,
    const float* __restrict__ Scale, float* __restrict__ Out) {
  __shared__ u32x4 ldsA[2][2][128][8];   // [buf][half][row][chunk16] = 64 KiB
  __shared__ u32x4 ldsB[2][2][128][8];

  const int tid  = threadIdx.x;
  const int lane = tid & 63;
  const int wid  = tid >> 6;
  const int wr   = wid >> 2;     // A half
  const int wc   = wid & 3;      // 64-col N slice
  const int wch  = wc >> 1;      // B half
  const int wcl  = wc & 1;

  int gid = (int)blockIdx.x;
  gid = (gid & 7) * (NWG >> 3) + (gid >> 3);   // bijective XCD swizzle (512%8==0)
  const int wg_m = gid / GRID_N;
  const int wg_n = gid % GRID_N;

  const int riA = lane & 15;
  const int c0  = lane >> 4;
  const int cs0 = c0 ^ (riA & 7);              // logical chunk c0   ^ row-swz
  const int cs1 = (4 + c0) ^ (riA & 7);        // logical chunk 4+c0 ^ row-swz

  // per-wave LDS read base pointers (AS3, 32-bit); m strides are literal offsets
  ldsp pA0c0 = (ldsp)&ldsA[0][wr][riA][cs0];
  ldsp pA0c1 = (ldsp)&ldsA[0][wr][riA][cs1];
  ldsp pA1c0 = (ldsp)&ldsA[1][wr][riA][cs0];
  ldsp pA1c1 = (ldsp)&ldsA[1][wr][riA][cs1];
  ldsp pB0c0 = (ldsp)&ldsB[0][wch][wcl * 64 + riA][cs0];
  ldsp pB0c1 = (ldsp)&ldsB[0][wch][wcl * 64 + riA][cs1];
  ldsp pB1c0 = (ldsp)&ldsB[1][wch][wcl * 64 + riA][cs0];
  ldsp pB1c1 = (ldsp)&ldsB[1][wch][wcl * 64 + riA][cs1];

  const u32x4* bA0 = wsA + (long)(wg_m * 2 + 0) * NT * 1024;
  const u32x4* bA1 = wsA + (long)(wg_m * 2 + 1) * NT * 1024;
  const u32x4* bB0 = wsB + (long)(wg_n * 2 + 0) * NT * 1024;
  const u32x4* bB1 = wsB + (long)(wg_n * 2 + 1) * NT * 1024;

  f32x4 acc[8][4];
#pragma unroll
  for (int m = 0; m < 8; ++m)
#pragma unroll
    for (int n = 0; n < 4; ++n) acc[m][n] = (f32x4){0.f, 0.f, 0.f, 0.f};

  bf16x8 aP[4][2], aQ[4][2], bP[2][2], bQ[2][2];

  // prologue: tile0 all 4 half-tiles + tile1 B halves; retire tile0 (vmcnt(4))
  STAGE(ldsB, 0, 0, bB0, 0) STAGE(ldsA, 0, 0, bA0, 0)
  STAGE(ldsB, 0, 1, bB1, 0) STAGE(ldsA, 0, 1, bA1, 0)
  STAGE(ldsB, 1, 0, bB0, 1) STAGE(ldsB, 1, 1, bB1, 1)
  WAITV(4); BAR();

#pragma unroll 1
  for (int it = 0; it < 31; ++it) {            // tiles 0..61
    const int t = 2 * it;
    TILE(pA0c0, pA0c1, pB0c0, pB0c1, 1, 0, t,     1, 1, WAITV(4))
    TILE(pA1c0, pA1c1, pB1c0, pB1c1, 0, 1, t + 1, 1, 1, WAITV(4))
  }
  TILE(pA0c0, pA0c1, pB0c0, pB0c1, 1, 0, 62, 1, 0, WAITV(0))  // stage A(63), drain
  TILE(pA1c0, pA1c1, pB1c0, pB1c1, 0, 1, 63, 0, 0, )          // compute only

  // epilogue: out = acc * scale[col]; C/D map: col=lane&15, row=(lane>>4)*4+j
  const int col0 = wg_n * BN + wc * 64 + (lane & 15);
  const int row0 = wg_m * BM + wr * 128 + ((lane >> 4) << 2);
#pragma unroll
  for (int n = 0; n < 4; ++n) {
    const int col = col0 + n * 16;
    const float s = Scale[col];
#pragma unroll
    for (int m = 0; m < 8; ++m) {
      const int r = row0 + m * 16;
#pragma unroll
      for (int j = 0; j < 4; ++j)
        Out[(long)(r + j) * DOUT + col] = acc[m][n][j] * s;
    }
  }
}

// ================= fallback: fused 128x128 (round-1, proven) =================
__global__ __launch_bounds__(256, 2) void gemm_fused_kernel(
    const float* __restrict__ X, const int* __restrict__ W,
    const int* __restrict__ Off, const float* __restrict__ Scale,
    float* __restrict__ Out) {
  __shared__ char ldsA[2][128 * 64 * 2];
  __shared__ char ldsB[2][128 * 64 * 2];

  const int tid  = threadIdx.x;
  const int lane = tid & 63;
  const int wid  = tid >> 6;
  const int fwr  = wid >> 1;
  const int fwc  = wid & 1;

  int gid = (int)blockIdx.x;
  gid = (gid & 7) * (2048 >> 3) + (gid >> 3);
  const int wg_m = gid / 32;
  const int wg_n = gid % 32;
  const int brow = wg_m * 128;
  const int bcol = wg_n * 128;

  f32x4 acc[4][4];
#pragma unroll
  for (int m = 0; m < 4; ++m)
#pragma unroll
    for (int n = 0; n < 4; ++n) acc[m][n] = (f32x4){0.f, 0.f, 0.f, 0.f};

  int aoff[2][4], boff[2][4];
#pragma unroll
  for (int kk = 0; kk < 2; ++kk)
#pragma unroll
    for (int m = 0; m < 4; ++m) {
      const int kb = kk * 64 + ((lane >> 4) << 4);
      const int ra = fwr * 64 + m * 16 + (lane & 15);
      const int rb = fwc * 64 + m * 16 + (lane & 15);
      aoff[kk][m] = ra * 128 + (kb ^ ((ra & 7) << 4));
      boff[kk][m] = rb * 128 + (kb ^ ((rb & 7) << 4));
    }

  long xo[8], wo[8];
  int lo[8], ofv[8];
#pragma unroll
  for (int i = 0; i < 8; ++i) {
    const int idx = tid + i * 256;
    const int row = idx >> 4, c4 = idx & 15;
    xo[i] = (long)(brow + row) * DIN + c4 * 4;
    wo[i] = (long)(bcol + row) * DIN + c4 * 4;
    lo[i] = row * 128 + ((c4 * 8) ^ ((row & 7) << 4));
    ofv[i] = Off[bcol + row];
  }
  {
#pragma unroll
    for (int i = 0; i < 8; ++i) {
      f32x4 f = *(const f32x4*)(X + xo[i]);
      u32x2 d;
      d[0] = pack_bf2_rne(f[0], f[1]);
      d[1] = pack_bf2_rne(f[2], f[3]);
      *(u32x2*)(&ldsA[0][lo[i]]) = d;
    }
#pragma unroll
    for (int i = 0; i < 8; ++i) {
      i32x4 w = *(const i32x4*)(W + wo[i]);
      u32x2 d;
      d[0] = pack_bf2_exact(w[0] - ofv[i], w[1] - ofv[i]);
      d[1] = pack_bf2_exact(w[2] - ofv[i], w[3] - ofv[i]);
      *(u32x2*)(&ldsB[0][lo[i]]) = d;
    }
  }
  __syncthreads();
#pragma unroll 1
  for (int kt = 0; kt < NT; ++kt) {
    const int cur = kt & 1;
    const bool pf = (kt + 1 < NT);
    f32x4 fa[8];
    i32x4 fb[8];
    if (pf) {
      const int ko = (kt + 1) * 64;
#pragma unroll
      for (int i = 0; i < 8; ++i) fa[i] = *(const f32x4*)(X + xo[i] + ko);
#pragma unroll
      for (int i = 0; i < 8; ++i) fb[i] = *(const i32x4*)(W + wo[i] + ko);
    }
#pragma unroll
    for (int kk = 0; kk < 2; ++kk) {
      bf16x8 fa2[4], fb2[4];
#pragma unroll
      for (int m = 0; m < 4; ++m)
        fa2[m] = __builtin_bit_cast(bf16x8, *(const u32x4*)(&ldsA[cur][aoff[kk][m]]));
#pragma unroll
      for (int n = 0; n < 4; ++n)
        fb2[n] = __builtin_bit_cast(bf16x8, *(const u32x4*)(&ldsB[cur][boff[kk][n]]));
#pragma unroll
      for (int m = 0; m < 4; ++m)
#pragma unroll
        for (int n = 0; n < 4; ++n)
          acc[m][n] = __builtin_amdgcn_mfma_f32_16x16x32_bf16(fa2[m], fb2[n], acc[m][n], 0, 0, 0);
    }
    if (pf) {
      char* dA = ldsA[cur ^ 1];
      char* dB = ldsB[cur ^ 1];
#pragma unroll
      for (int i = 0; i < 8; ++i) {
        u32x2 d;
        d[0] = pack_bf2_rne(fa[i][0], fa[i][1]);
        d[1] = pack_bf2_rne(fa[i][2], fa[i][3]);
        *(u32x2*)(&dA[lo[i]]) = d;
      }
#pragma unroll
      for (int i = 0; i < 8; ++i) {
        u32x2 d;
        d[0] = pack_bf2_exact(fb[i][0] - ofv[i], fb[i][1] - ofv[i]);
        d[1] = pack_bf2_exact(fb[i][2] - ofv[i], fb[i][3] - ofv[i]);
        *(u32x2*)(&dB[lo[i]]) = d;
      }
    }
    __syncthreads();
  }

  const int col0 = bcol + fwc * 64 + (lane & 15);
  const int row0 = brow + fwr * 64 + ((lane >> 4) << 2);
#pragma unroll
  for (int n = 0; n < 4; ++n) {
    const int col = col0 + n * 16;
    const float s = Scale[col];
#pragma unroll
    for (int m = 0; m < 4; ++m) {
      const int r = row0 + m * 16;
#pragma unroll
      for (int j = 0; j < 4; ++j)
        Out[(long)(r + j) * DOUT + col] = acc[m][n][j] * s;
    }
  }
}

extern "C" void kernel_launch(void* const* d_in, const int* in_sizes, int n_in,
                              void* d_out, int out_size, void* d_ws, size_t ws_size,
                              hipStream_t stream) {
  (void)in_sizes; (void)n_in; (void)out_size;
  const float* X  = (const float*)d_in[0];
  const int*   W  = (const int*)d_in[1];
  const float* Sc = (const float*)d_in[2];
  const int*   Of = (const int*)d_in[3];
  float* Out = (float*)d_out;

  const size_t needA = (size_t)MTOT * DIN * 2;
  const size_t needB = (size_t)DOUT * DIN * 2;
  if (ws_size >= needA + needB) {
    u32x4* wsA = (u32x4*)d_ws;
    u32x4* wsB = (u32x4*)((char*)d_ws + needA);
    conv_kernel<<<3072, 256, 0, stream>>>(X, wsA, W, Of, wsB);
    gemm8_kernel<<<NWG, 512, 0, stream>>>(wsA, wsB, Sc, Out);
  } else {
    gemm_fused_kernel<<<2048, 256, 0, stream>>>(X, W, Of, Sc, Out);
  }
}